// Round 9
// baseline (651.391 us; speedup 1.0000x reference)
//
#include <hip/hip_runtime.h>
#include <hip/hip_bf16.h>
#include <math.h>

#define VOCAB 32000
#define DIM 1024
#define BB 2
#define SS 512
#define BS (BB*SS)
#define MASK_ID 31999
#define EXPAND_ID 31998
#define NSTEPS 4
#define TOPK 50
#define NR 8
#define NEGF (-3.4028234663852886e38f)

#define NDCL 16            // logits K-chunks (DL=64)
#define DL 64
#define LNBX 63            // col-blocks of 512 cols (last partial)
#define NCH 500            // 64-col chunks per row
#define THRRANK 63         // T = 64th-largest chunk max (>=64 values >= T >= top-50)
#define CAP 768            // candidate capacity
#define CFBLK 256          // comb/finish grid blocks (32 x NR)

// -------- persistent device state (re-initialized every kernel_launch) ------
__device__ int      g_x[BS];
__device__ int      g_x0[BS];
__device__ int      g_tok_used[BS];
__device__ float    g_conf[BS];
__device__ int      g_row_tok[NR];     // CAS-compacted: active rows 0..nact-1
__device__ float    g_row_conf[NR];
__device__ int      g_row_x0[NR];
__device__ float    g_h[NR][DIM];
__device__ float    g_lpart[NDCL][NR][VOCAB];
__device__ float    g_logits[NR][VOCAB];
__device__ float    g_step_conf[NSTEPS];
__device__ float    g_cmax[NR][NCH];
__device__ int      g_camax[NR][NCH];
__device__ float    g_cz[NR][NCH];
__device__ int      g_done;

__device__ inline unsigned keyf(float f) {
    unsigned b = __float_as_uint(f);
    return b ^ ((b & 0x80000000u) ? 0xFFFFFFFFu : 0x80000000u);
}

// 1 block, 1024 threads: init all state + step-0 requests (BS == 1024)
__global__ __launch_bounds__(1024) void k_start(const int* __restrict__ x) {
    int p = threadIdx.x;
    g_x[p] = x[p];
    g_tok_used[p] = -1;
    g_conf[p] = NEGF;
    g_x0[p] = 0;
    if (p < NR) g_row_tok[p] = -1;
    if (p == 0) g_done = 0;
    __syncthreads();
    if (g_x[p] != MASK_ID) return;
    int s = p & (SS - 1);
    int t = g_x[(s == 0) ? p : p - 1];
    for (int r = 0; r < NR; r++) {
        int old = atomicCAS(&g_row_tok[r], -1, t);
        if (old == -1 || old == t) return;
    }
}

// h = tanh(emb[tok] @ W1), full-K: grid 32, block 1024 = 32 cols x 32 K-groups
__global__ __launch_bounds__(1024) void k_h(const float* __restrict__ emb,
                                            const float* __restrict__ W1) {
    __shared__ int   s_tok[NR];
    __shared__ int   s_nact;
    __shared__ float se[NR][DIM];      // 32 KB
    __shared__ float red[32][33];      // padded
    int tid = threadIdx.x, bid = blockIdx.x;
    if (tid == 0) {
        int n = 0;
        while (n < NR && g_row_tok[n] >= 0) n++;
        s_nact = n;
    }
    if (tid < NR) s_tok[tid] = g_row_tok[tid];
    __syncthreads();
    const int nact = s_nact;
    if (nact == 0) return;
    for (int i = tid; i < nact * DIM; i += 1024) {
        int r = i >> 10, d = i & (DIM - 1);
        se[r][d] = emb[(size_t)s_tok[r] * DIM + d];
    }
    __syncthreads();
    const int ct = tid & 31, kg = tid >> 5;
    const int col = bid * 32 + ct;
    float acc[NR];
    #pragma unroll
    for (int r = 0; r < NR; r++) acc[r] = 0.f;
    #pragma unroll 4
    for (int dd = 0; dd < 32; dd++) {
        int d = kg * 32 + dd;
        float w = W1[(size_t)d * DIM + col];
        #pragma unroll
        for (int r = 0; r < NR; r++)
            if (r < nact) acc[r] += se[r][d] * w;
    }
    for (int r = 0; r < nact; r++) {           // nact is block-uniform
        red[kg][ct] = acc[r];
        __syncthreads();
        for (int o = 16; o; o >>= 1) {
            if (kg < o) red[kg][ct] += red[kg + o][ct];
            __syncthreads();
        }
        if (kg == 0) g_h[r][col] = tanhf(red[0][ct]);
        __syncthreads();
    }
}

// row-count-specialized split-K accumulate (static register indices)
template<int NA>
__device__ __forceinline__ void accumL(const float* __restrict__ Wout,
                                       const float (*sh)[DL], int dc, int c) {
    float4 acc[NA];
    #pragma unroll
    for (int r = 0; r < NA; r++) acc[r] = make_float4(0.f, 0.f, 0.f, 0.f);
    const float* W = Wout + (size_t)dc * DL * VOCAB + c;
    #pragma unroll 4
    for (int dd = 0; dd < DL; dd++) {
        float4 w = *(const float4*)(W + (size_t)dd * VOCAB);
        #pragma unroll
        for (int r = 0; r < NA; r++) {
            float s = sh[r][dd];
            acc[r].x += s * w.x; acc[r].y += s * w.y;
            acc[r].z += s * w.z; acc[r].w += s * w.w;
        }
    }
    #pragma unroll
    for (int r = 0; r < NA; r++)
        *(float4*)&g_lpart[dc][r][c] = acc[r];
}

// logits split-K partials: grid (63, 16), block 128 (4 cols/thread)
__global__ __launch_bounds__(128) void k_logits(const float* __restrict__ Wout) {
    __shared__ float sh[NR][DL];       // 2 KB
    __shared__ int   s_nact;
    int tid = threadIdx.x;
    int dc = blockIdx.y;
    if (tid == 0) {
        int n = 0;
        while (n < NR && g_row_tok[n] >= 0) n++;
        s_nact = n;
    }
    __syncthreads();
    const int nact = s_nact;
    if (nact == 0) return;
    for (int i = tid; i < nact * DL; i += 128) {
        int r = i >> 6, dd = i & (DL - 1);
        sh[r][dd] = g_h[r][dc * DL + dd];
    }
    __syncthreads();
    int c = blockIdx.x * 512 + tid * 4;
    if (c >= VOCAB) return;
    switch (nact) {
        case 1: accumL<1>(Wout, sh, dc, c); break;
        case 2: accumL<2>(Wout, sh, dc, c); break;
        case 3: accumL<3>(Wout, sh, dc, c); break;
        case 4: accumL<4>(Wout, sh, dc, c); break;
        default: accumL<NR>(Wout, sh, dc, c); break;
    }
}

// combine + penalty + wave chunk-stats, then LAST block runs the finish.
// grid (32, NR) = 256 blocks, block 1024 = 16 waves (16 chunks of 64 cols)
__global__ __launch_bounds__(1024) void k_cf(int step, float* __restrict__ out) {
    __shared__ float    red_f[1024];       // 4 KB
    __shared__ int      red_i[1024];       // 4 KB
    __shared__ float    cmv[512];          // 2 KB
    __shared__ float    candL[NR][CAP];    // 24 KB
    __shared__ int      cand_n[NR];
    __shared__ float    sorted_[NR][TOPK]; // 1.6 KB
    __shared__ float    s_mx[NR];
    __shared__ int      s_am[NR];
    __shared__ float    s_Zr[NR];
    __shared__ unsigned s_thr[NR];
    __shared__ int      s_nact;
    __shared__ int      s_tail;

    int tid = threadIdx.x;
    if (tid == 0) {
        int n = 0;
        while (n < NR && g_row_tok[n] >= 0) n++;
        s_nact = n;
    }
    __syncthreads();
    const int nact = s_nact;

    // ---- comb + chunk stats ----
    {
        int r = blockIdx.y;
        if (r < nact) {
            int wv = tid >> 6, lane = tid & 63;
            int chunk = blockIdx.x * 16 + wv;          // < 512
            if (chunk < NCH) {
                int c = chunk * 64 + lane;
                float v = 0.f;
                #pragma unroll
                for (int dc = 0; dc < NDCL; dc++) v += g_lpart[dc][r][c];
                if (c == EXPAND_ID) v -= 1e9f;
                g_logits[r][c] = v;
                float bv = v; int bi = c;
                #pragma unroll
                for (int off = 1; off < 64; off <<= 1) {
                    float ov = __shfl_xor(bv, off, 64);
                    int   oi = __shfl_xor(bi, off, 64);
                    if (ov > bv || (ov == bv && oi < bi)) { bv = ov; bi = oi; }
                }
                float z = expf(v - bv);
                #pragma unroll
                for (int off = 1; off < 64; off <<= 1)
                    z += __shfl_xor(z, off, 64);
                if (lane == 0) {
                    g_cmax[r][chunk]  = bv;
                    g_camax[r][chunk] = bi;
                    g_cz[r][chunk]    = z;
                }
            }
        }
    }
    // ---- done-counter: last of 256 blocks proceeds to finish ----
    __threadfence();
    if (tid == 0) s_tail = (atomicAdd(&g_done, 1) == CFBLK - 1);
    __syncthreads();
    if (!s_tail) return;
    __threadfence();
    if (tid < NR) cand_n[tid] = 0;
    __syncthreads();

    int r = tid >> 7, lane = tid & 127;
    bool act = (r < nact);

    // --- Phase A: per-row reduce over 500 chunks (128-lane group per row) ---
    float bv = NEGF; int bi = 0x7fffffff;
    if (act) {
        #pragma unroll
        for (int j = 0; j < 4; j++) {
            int ch = lane + j * 128;
            if (ch < NCH) {
                float v2 = g_cmax[r][ch]; int i2 = g_camax[r][ch];
                if (v2 > bv || (v2 == bv && i2 < bi)) { bv = v2; bi = i2; }
            }
        }
    }
    red_f[tid] = bv; red_i[tid] = bi;
    __syncthreads();
    for (int o = 64; o; o >>= 1) {
        if (lane < o) {
            if (red_f[tid + o] > red_f[tid] ||
                (red_f[tid + o] == red_f[tid] && red_i[tid + o] < red_i[tid])) {
                red_f[tid] = red_f[tid + o]; red_i[tid] = red_i[tid + o];
            }
        }
        __syncthreads();
    }
    if (act && lane == 0) { s_mx[r] = red_f[tid]; s_am[r] = red_i[tid]; }
    __syncthreads();
    float z = 0.f;
    if (act) {
        float mx = s_mx[r];
        #pragma unroll
        for (int j = 0; j < 4; j++) {
            int ch = lane + j * 128;
            if (ch < NCH) z += g_cz[r][ch] * expf(g_cmax[r][ch] - mx);
        }
    }
    red_f[tid] = z;
    __syncthreads();
    for (int o = 64; o; o >>= 1) {
        if (lane < o) red_f[tid] += red_f[tid + o];
        __syncthreads();
    }
    if (act && lane == 0) s_Zr[r] = red_f[tid];
    __syncthreads();

    // --- Phase B: threshold = 64th-largest chunk max (rows serial) ---
    for (int rr = 0; rr < nact; rr++) {
        if (tid < 512) cmv[tid] = (tid < NCH) ? g_cmax[rr][tid] : NEGF;
        __syncthreads();
        if (tid < NCH) {
            unsigned kt = keyf(cmv[tid]);
            int rank = 0;
            for (int j = 0; j < NCH; j++) {
                unsigned kj = keyf(cmv[j]);
                rank += (kj > kt) || (kj == kt && j < tid);
            }
            if (rank == THRRANK) s_thr[rr] = kt;
        }
        __syncthreads();
    }

    // --- Phase C: gather candidates >= threshold (rows serial) ---
    for (int rr = 0; rr < nact; rr++) {
        unsigned T = s_thr[rr];
        const float4* L4 = (const float4*)g_logits[rr];
        #pragma unroll
        for (int i = 0; i < 8; i++) {
            int idx = i * 1024 + tid;
            if (idx < VOCAB / 4) {
                float4 v4 = L4[idx];
                float vv[4] = {v4.x, v4.y, v4.z, v4.w};
                #pragma unroll
                for (int q = 0; q < 4; q++) {
                    if (keyf(vv[q]) >= T) {
                        int j = atomicAdd(&cand_n[rr], 1);
                        if (j < CAP) candL[rr][j] = vv[q];
                    }
                }
            }
        }
    }
    __syncthreads();

    // --- Phase D: rank-sort top-50 + conf (128-lane group per row) ---
    if (act) {
        int n = cand_n[r]; if (n > CAP) n = CAP;
        for (int i = lane; i < n; i += 128) {
            unsigned ki = keyf(candL[r][i]);
            int rank = 0;
            for (int j = 0; j < n; j++) {
                unsigned kj = keyf(candL[r][j]);
                rank += (kj > ki) || (kj == ki && j < i);
            }
            if (rank < TOPK) sorted_[r][rank] = candL[r][i];
        }
    }
    __syncthreads();
    if (act && lane == 0) {
        int n = cand_n[r]; if (n > CAP) n = CAP;
        int m = n; if (m > TOPK) m = TOPK;
        float mx  = s_mx[r];
        float run = expf(sorted_[r][0] - mx);    // == 1
        float lim = 0.9f * s_Zr[r];
        for (int j = 1; j < m; j++) {
            if (run > lim) break;                // top-p removal boundary
            run += expf(sorted_[r][j] - mx);
        }
        g_row_conf[r] = 1.0f / run;
        g_row_x0[r]   = s_am[r];
    }
    __syncthreads();

    // --- Phase E: scatter + global argmax + reveal + next requests ---
    int p = tid;
    float myconf;
    if (g_x[p] != MASK_ID) {
        myconf = NEGF; g_conf[p] = NEGF;
    } else {
        myconf = g_conf[p];                      // cached from earlier steps
        int s = p & (SS - 1);
        int t = g_x[(s == 0) ? p : p - 1];
        #pragma unroll
        for (int rr = 0; rr < NR; rr++) {
            if (g_row_tok[rr] == t) {
                myconf = g_row_conf[rr];
                g_conf[p] = myconf;
                g_x0[p]   = g_row_x0[rr];
                g_tok_used[p] = t;
                break;
            }
        }
    }
    red_f[p] = myconf; red_i[p] = p;
    __syncthreads();
    for (int o = 512; o; o >>= 1) {
        if (p < o) {
            if (red_f[p + o] > red_f[p] ||
                (red_f[p + o] == red_f[p] && red_i[p + o] < red_i[p])) {
                red_f[p] = red_f[p + o]; red_i[p] = red_i[p + o];
            }
        }
        __syncthreads();
    }
    if (p == 0) {
        float c = red_f[0]; int idx = red_i[0];
        g_step_conf[step] = c;
        if (c > 0.f) g_x[idx] = g_x0[idx];       // any-mask guard: conf > 0
        g_done = 0;                              // reset for next step
    }
    __syncthreads();
    if (step == NSTEPS - 1) {
        out[p] = (float)g_x[p];
        if (p < NSTEPS) out[BS + p] = g_step_conf[p];
        return;
    }
    // next-step requests (post-reveal)
    if (p < NR) g_row_tok[p] = -1;
    __syncthreads();
    if (g_x[p] != MASK_ID) return;
    int s2 = p & (SS - 1);
    int t2 = g_x[(s2 == 0) ? p : p - 1];
    if (t2 == g_tok_used[p]) return;
    for (int rr = 0; rr < NR; rr++) {
        int old = atomicCAS(&g_row_tok[rr], -1, t2);
        if (old == -1 || old == t2) return;
    }
}

extern "C" void kernel_launch(void* const* d_in, const int* in_sizes, int n_in,
                              void* d_out, int out_size, void* d_ws, size_t ws_size,
                              hipStream_t stream) {
    const int*   x    = (const int*)  d_in[0];
    const float* emb  = (const float*)d_in[1];
    const float* W1   = (const float*)d_in[2];
    const float* Wout = (const float*)d_in[3];
    float*       out  = (float*)d_out;

    k_start<<<1, 1024, 0, stream>>>(x);
    for (int s = 0; s < NSTEPS; s++) {
        k_h<<<32, 1024, 0, stream>>>(emb, W1);
        k_logits<<<dim3(LNBX, NDCL), 128, 0, stream>>>(Wout);
        k_cf<<<dim3(32, NR), 1024, 0, stream>>>(s, out);
    }
}

// Round 10
// 378.405 us; speedup vs baseline: 1.7214x; 1.7214x over previous
//
#include <hip/hip_runtime.h>
#include <hip/hip_bf16.h>
#include <math.h>

#define VOCAB 32000
#define DIM 1024
#define BB 2
#define SS 512
#define BS (BB*SS)
#define MASK_ID 31999
#define EXPAND_ID 31998
#define NSTEPS 4
#define TOPK 50
#define NR 8
#define NEGF (-3.4028234663852886e38f)

#define NDCL 32            // logits K-chunks (DL=32) -> 4096 waves total
#define DL 32
#define LNBX 32            // col-blocks of 1024 cols
#define NCH 500            // 64-col chunks per row
#define THRRANK 63         // T = 64th-largest chunk max (>=64 values >= T >= top-50)
#define CAP 768            // candidate capacity

// -------- persistent device state (re-initialized every kernel_launch) ------
__device__ int      g_x[BS];
__device__ int      g_x0[BS];
__device__ int      g_tok_used[BS];
__device__ float    g_conf[BS];
__device__ int      g_row_tok[NR];     // CAS-compacted: active rows 0..nact-1
__device__ float    g_row_conf[NR];
__device__ int      g_row_x0[NR];
__device__ float    g_h[NR][DIM];
__device__ float    g_lpart[NDCL][NR][VOCAB];
__device__ float    g_logits[NR][VOCAB];
__device__ float    g_step_conf[NSTEPS];
__device__ float    g_cmax[NR][NCH];
__device__ int      g_camax[NR][NCH];
__device__ float    g_cz[NR][NCH];

__device__ inline unsigned keyf(float f) {
    unsigned b = __float_as_uint(f);
    return b ^ ((b & 0x80000000u) ? 0xFFFFFFFFu : 0x80000000u);
}

// 1 block, 1024 threads: init all state + step-0 requests (BS == 1024)
__global__ __launch_bounds__(1024) void k_start(const int* __restrict__ x) {
    int p = threadIdx.x;
    g_x[p] = x[p];
    g_tok_used[p] = -1;
    g_conf[p] = NEGF;
    g_x0[p] = 0;
    if (p < NR) g_row_tok[p] = -1;
    __syncthreads();
    if (g_x[p] != MASK_ID) return;
    int s = p & (SS - 1);
    int t = g_x[(s == 0) ? p : p - 1];
    for (int r = 0; r < NR; r++) {
        int old = atomicCAS(&g_row_tok[r], -1, t);
        if (old == -1 || old == t) return;
    }
}

// h = tanh(emb[tok] @ W1), full-K: grid 32, block 1024 = 32 cols x 32 K-groups
__global__ __launch_bounds__(1024) void k_h(const float* __restrict__ emb,
                                            const float* __restrict__ W1) {
    __shared__ int   s_tok[NR];
    __shared__ int   s_nact;
    __shared__ float se[NR][DIM];      // 32 KB
    __shared__ float red[32][33];      // padded
    int tid = threadIdx.x, bid = blockIdx.x;
    if (tid == 0) {
        int n = 0;
        while (n < NR && g_row_tok[n] >= 0) n++;
        s_nact = n;
    }
    if (tid < NR) s_tok[tid] = g_row_tok[tid];
    __syncthreads();
    const int nact = s_nact;
    if (nact == 0) return;
    for (int i = tid; i < nact * DIM; i += 1024) {
        int r = i >> 10, d = i & (DIM - 1);
        se[r][d] = emb[(size_t)s_tok[r] * DIM + d];
    }
    __syncthreads();
    const int ct = tid & 31, kg = tid >> 5;
    const int col = bid * 32 + ct;
    float acc[NR];
    #pragma unroll
    for (int r = 0; r < NR; r++) acc[r] = 0.f;
    #pragma unroll 4
    for (int dd = 0; dd < 32; dd++) {
        int d = kg * 32 + dd;
        float w = W1[(size_t)d * DIM + col];
        #pragma unroll
        for (int r = 0; r < NR; r++)
            if (r < nact) acc[r] += se[r][d] * w;
    }
    for (int r = 0; r < nact; r++) {           // nact is block-uniform
        red[kg][ct] = acc[r];
        __syncthreads();
        for (int o = 16; o; o >>= 1) {
            if (kg < o) red[kg][ct] += red[kg + o][ct];
            __syncthreads();
        }
        if (kg == 0) g_h[r][col] = tanhf(red[0][ct]);
        __syncthreads();
    }
}

// row-count-specialized split-K accumulate (static register indices)
template<int NA>
__device__ __forceinline__ void accumL(const float* __restrict__ Wout,
                                       const float (*sh)[DL], int dc, int c) {
    float4 acc[NA];
    #pragma unroll
    for (int r = 0; r < NA; r++) acc[r] = make_float4(0.f, 0.f, 0.f, 0.f);
    const float* W = Wout + (size_t)dc * DL * VOCAB + c;
    #pragma unroll 4
    for (int dd = 0; dd < DL; dd++) {
        float4 w = *(const float4*)(W + (size_t)dd * VOCAB);
        #pragma unroll
        for (int r = 0; r < NA; r++) {
            float s = sh[r][dd];
            acc[r].x += s * w.x; acc[r].y += s * w.y;
            acc[r].z += s * w.z; acc[r].w += s * w.w;
        }
    }
    #pragma unroll
    for (int r = 0; r < NA; r++)
        *(float4*)&g_lpart[dc][r][c] = acc[r];
}

// logits split-K partials: grid (LNBX=32, NDCL=32), block 256, 4 cols/thread
// 1024 blocks x 4 waves = 4096 waves = 16/CU = 4/SIMD (latency hiding)
__global__ __launch_bounds__(256) void k_logits(const float* __restrict__ Wout) {
    __shared__ float sh[NR][DL];       // 1 KB
    __shared__ int   s_nact;
    int tid = threadIdx.x;
    int dc = blockIdx.y;
    if (tid == 0) {
        int n = 0;
        while (n < NR && g_row_tok[n] >= 0) n++;
        s_nact = n;
    }
    __syncthreads();
    const int nact = s_nact;
    if (nact == 0) return;
    if (tid < nact * DL) {
        int r = tid >> 5, dd = tid & (DL - 1);
        sh[r][dd] = g_h[r][dc * DL + dd];
    }
    __syncthreads();
    int c = blockIdx.x * 1024 + tid * 4;
    if (c >= VOCAB) return;
    switch (nact) {
        case 1: accumL<1>(Wout, sh, dc, c); break;
        case 2: accumL<2>(Wout, sh, dc, c); break;
        case 3: accumL<3>(Wout, sh, dc, c); break;
        case 4: accumL<4>(Wout, sh, dc, c); break;
        default: accumL<NR>(Wout, sh, dc, c); break;
    }
}

// combine + penalty + per-64-chunk wave stats (no __syncthreads):
// grid (125, NR), block 256 = 4 independent waves
__global__ __launch_bounds__(256) void k_comb_stats() {
    int r = blockIdx.y;
    if (g_row_tok[r] < 0) return;
    int wv = threadIdx.x >> 6, lane = threadIdx.x & 63;
    int chunk = blockIdx.x * 4 + wv;             // < 500
    int c = chunk * 64 + lane;                   // < 32000
    float v = 0.f;
    #pragma unroll
    for (int dc = 0; dc < NDCL; dc++) v += g_lpart[dc][r][c];
    if (c == EXPAND_ID) v -= 1e9f;
    g_logits[r][c] = v;
    // wave max + first-index argmax
    float bv = v; int bi = c;
    #pragma unroll
    for (int off = 1; off < 64; off <<= 1) {
        float ov = __shfl_xor(bv, off, 64);
        int   oi = __shfl_xor(bi, off, 64);
        if (ov > bv || (ov == bv && oi < bi)) { bv = ov; bi = oi; }
    }
    float z = expf(v - bv);
    #pragma unroll
    for (int off = 1; off < 64; off <<= 1)
        z += __shfl_xor(z, off, 64);
    if (lane == 0) {
        g_cmax[r][chunk]  = bv;
        g_camax[r][chunk] = bi;
        g_cz[r][chunk]    = z;
    }
}

// 1 block, 1024 threads: chunk-reduce, chunk-max rank-select threshold,
// gather, sort+conf, scatter, argmax, reveal, next requests, (last: output)
__global__ __launch_bounds__(1024) void k_finish(int step, float* __restrict__ out) {
    __shared__ float    red_f[1024];       // 4 KB
    __shared__ int      red_i[1024];       // 4 KB
    __shared__ float    cmv[512];          // 2 KB
    __shared__ float    candL[NR][CAP];    // 24 KB
    __shared__ int      cand_n[NR];
    __shared__ float    sorted_[NR][TOPK]; // 1.6 KB
    __shared__ float    s_mx[NR];
    __shared__ int      s_am[NR];
    __shared__ float    s_Zr[NR];
    __shared__ unsigned s_thr[NR];
    __shared__ int      s_nact;

    int tid = threadIdx.x;
    if (tid == 0) {
        int n = 0;
        while (n < NR && g_row_tok[n] >= 0) n++;
        s_nact = n;
    }
    if (tid < NR) cand_n[tid] = 0;
    __syncthreads();
    const int nact = s_nact;
    int r = tid >> 7, lane = tid & 127;
    bool act = (r < nact);

    // --- Phase A: per-row reduce over 500 chunks (128-lane group per row) ---
    float bv = NEGF; int bi = 0x7fffffff;
    if (act) {
        #pragma unroll
        for (int j = 0; j < 4; j++) {
            int ch = lane + j * 128;
            if (ch < NCH) {
                float v2 = g_cmax[r][ch]; int i2 = g_camax[r][ch];
                if (v2 > bv || (v2 == bv && i2 < bi)) { bv = v2; bi = i2; }
            }
        }
    }
    red_f[tid] = bv; red_i[tid] = bi;
    __syncthreads();
    for (int o = 64; o; o >>= 1) {
        if (lane < o) {
            if (red_f[tid + o] > red_f[tid] ||
                (red_f[tid + o] == red_f[tid] && red_i[tid + o] < red_i[tid])) {
                red_f[tid] = red_f[tid + o]; red_i[tid] = red_i[tid + o];
            }
        }
        __syncthreads();
    }
    if (act && lane == 0) { s_mx[r] = red_f[tid]; s_am[r] = red_i[tid]; }
    __syncthreads();
    float z = 0.f;
    if (act) {
        float mx = s_mx[r];
        #pragma unroll
        for (int j = 0; j < 4; j++) {
            int ch = lane + j * 128;
            if (ch < NCH) z += g_cz[r][ch] * expf(g_cmax[r][ch] - mx);
        }
    }
    red_f[tid] = z;
    __syncthreads();
    for (int o = 64; o; o >>= 1) {
        if (lane < o) red_f[tid] += red_f[tid + o];
        __syncthreads();
    }
    if (act && lane == 0) s_Zr[r] = red_f[tid];
    __syncthreads();

    // --- Phase B: threshold = 64th-largest chunk max (rows serial) ---
    for (int rr = 0; rr < nact; rr++) {
        if (tid < 512) cmv[tid] = (tid < NCH) ? g_cmax[rr][tid] : NEGF;
        __syncthreads();
        if (tid < NCH) {
            unsigned kt = keyf(cmv[tid]);
            int rank = 0;
            for (int j = 0; j < NCH; j++) {
                unsigned kj = keyf(cmv[j]);
                rank += (kj > kt) || (kj == kt && j < tid);
            }
            if (rank == THRRANK) s_thr[rr] = kt;
        }
        __syncthreads();
    }

    // --- Phase C: gather candidates >= threshold (rows serial) ---
    for (int rr = 0; rr < nact; rr++) {
        unsigned T = s_thr[rr];
        const float4* L4 = (const float4*)g_logits[rr];
        #pragma unroll
        for (int i = 0; i < 8; i++) {
            int idx = i * 1024 + tid;
            if (idx < VOCAB / 4) {
                float4 v4 = L4[idx];
                float vv[4] = {v4.x, v4.y, v4.z, v4.w};
                #pragma unroll
                for (int q = 0; q < 4; q++) {
                    if (keyf(vv[q]) >= T) {
                        int j = atomicAdd(&cand_n[rr], 1);
                        if (j < CAP) candL[rr][j] = vv[q];
                    }
                }
            }
        }
    }
    __syncthreads();

    // --- Phase D: rank-sort top-50 + conf (128-lane group per row) ---
    if (act) {
        int n = cand_n[r]; if (n > CAP) n = CAP;
        for (int i = lane; i < n; i += 128) {
            unsigned ki = keyf(candL[r][i]);
            int rank = 0;
            for (int j = 0; j < n; j++) {
                unsigned kj = keyf(candL[r][j]);
                rank += (kj > ki) || (kj == ki && j < i);
            }
            if (rank < TOPK) sorted_[r][rank] = candL[r][i];
        }
    }
    __syncthreads();
    if (act && lane == 0) {
        int n = cand_n[r]; if (n > CAP) n = CAP;
        int m = n; if (m > TOPK) m = TOPK;
        float mx  = s_mx[r];
        float run = expf(sorted_[r][0] - mx);    // == 1
        float lim = 0.9f * s_Zr[r];
        for (int j = 1; j < m; j++) {
            if (run > lim) break;                // top-p removal boundary
            run += expf(sorted_[r][j] - mx);
        }
        g_row_conf[r] = 1.0f / run;
        g_row_x0[r]   = s_am[r];
    }
    __syncthreads();

    // --- Phase E: scatter + global argmax + reveal + next requests ---
    int p = tid;
    float myconf;
    if (g_x[p] != MASK_ID) {
        myconf = NEGF; g_conf[p] = NEGF;
    } else {
        myconf = g_conf[p];                      // cached from earlier steps
        int s = p & (SS - 1);
        int t = g_x[(s == 0) ? p : p - 1];
        #pragma unroll
        for (int rr = 0; rr < NR; rr++) {
            if (g_row_tok[rr] == t) {
                myconf = g_row_conf[rr];
                g_conf[p] = myconf;
                g_x0[p]   = g_row_x0[rr];
                g_tok_used[p] = t;
                break;
            }
        }
    }
    red_f[p] = myconf; red_i[p] = p;
    __syncthreads();
    for (int o = 512; o; o >>= 1) {
        if (p < o) {
            if (red_f[p + o] > red_f[p] ||
                (red_f[p + o] == red_f[p] && red_i[p + o] < red_i[p])) {
                red_f[p] = red_f[p + o]; red_i[p] = red_i[p + o];
            }
        }
        __syncthreads();
    }
    if (p == 0) {
        float c = red_f[0]; int idx = red_i[0];
        g_step_conf[step] = c;
        if (c > 0.f) g_x[idx] = g_x0[idx];       // any-mask guard: conf > 0
    }
    __syncthreads();
    if (step == NSTEPS - 1) {
        out[p] = (float)g_x[p];
        if (p < NSTEPS) out[BS + p] = g_step_conf[p];
        return;
    }
    // next-step requests (post-reveal)
    if (p < NR) g_row_tok[p] = -1;
    __syncthreads();
    if (g_x[p] != MASK_ID) return;
    int s2 = p & (SS - 1);
    int t2 = g_x[(s2 == 0) ? p : p - 1];
    if (t2 == g_tok_used[p]) return;
    for (int rr = 0; rr < NR; rr++) {
        int old = atomicCAS(&g_row_tok[rr], -1, t2);
        if (old == -1 || old == t2) return;
    }
}

extern "C" void kernel_launch(void* const* d_in, const int* in_sizes, int n_in,
                              void* d_out, int out_size, void* d_ws, size_t ws_size,
                              hipStream_t stream) {
    const int*   x    = (const int*)  d_in[0];
    const float* emb  = (const float*)d_in[1];
    const float* W1   = (const float*)d_in[2];
    const float* Wout = (const float*)d_in[3];
    float*       out  = (float*)d_out;

    k_start<<<1, 1024, 0, stream>>>(x);
    for (int s = 0; s < NSTEPS; s++) {
        k_h<<<32, 1024, 0, stream>>>(emb, W1);
        k_logits<<<dim3(LNBX, NDCL), 256, 0, stream>>>(Wout);
        k_comb_stats<<<dim3(125, NR), 256, 0, stream>>>();
        k_finish<<<1, 1024, 0, stream>>>(s, out);
    }
}

// Round 11
// 229.761 us; speedup vs baseline: 2.8351x; 1.6470x over previous
//
#include <hip/hip_runtime.h>
#include <math.h>

#define VOCAB 32000
#define DIM 1024
#define SS 512
#define BS 1024
#define MASK_ID 31999
#define EXPAND_ID 31998
#define NSTEPS 4
#define TOPK 50
#define PW 4               // max new rows per pass
#define ROWS 16            // total row-cache slots
#define KC 16              // h K-chunks (64 d each)
#define NDCL 16            // logits K-chunks (64 d each)
#define NCH 500            // 64-col chunks per row
#define THRRANK 49         // T = 50th-largest chunk max -> >=50 values >= T
#define CAP 768
#define NEGF (-3.4028234663852886e38f)

// -------- persistent device state (re-initialized every kernel_launch) ------
__device__ int   g_x[BS];
__device__ int   g_tok[ROWS];      // cached-row tokens (CAS/dedup appended)
__device__ int   g_ntok;           // total tokens (incl. not-yet-computed)
__device__ int   g_pbase;          // base slot of current pass
__device__ int   g_pn;             // row count of current pass
__device__ float g_hp[KC][PW][DIM];
__device__ float g_lpart[NDCL][PW][VOCAB];
__device__ float g_rows[ROWS][VOCAB];
__device__ float g_cmax[ROWS][NCH];
__device__ int   g_camax[ROWS][NCH];
__device__ float g_cz[ROWS][NCH];
__device__ int   g_rowx0[ROWS];    // per-row first-index argmax (= token id)
__device__ float g_rowconf[ROWS];

__device__ inline unsigned keyf(float f) {
    unsigned b = __float_as_uint(f);
    return b ^ ((b & 0x80000000u) ? 0xFFFFFFFFu : 0x80000000u);
}

// 1 block, 1024 threads: init + pass-1 token set (CAS dedup)
__global__ __launch_bounds__(1024) void k_start(const int* __restrict__ x) {
    int p = threadIdx.x;
    g_x[p] = x[p];
    if (p < ROWS) g_tok[p] = -1;
    __syncthreads();
    if (g_x[p] == MASK_ID) {
        int s = p & (SS - 1);
        int t = g_x[(s == 0) ? p : p - 1];
        for (int r = 0; r < PW; r++) {
            int old = atomicCAS(&g_tok[r], -1, t);
            if (old == -1 || old == t) break;
        }
    }
    __syncthreads();
    if (p == 0) {
        int n = 0;
        while (n < PW && g_tok[n] >= 0) n++;
        g_pbase = 0; g_pn = n; g_ntok = n;
    }
}

// h partials for current pass: grid (8, KC), block 128
__global__ __launch_bounds__(128) void k_h_part(const float* __restrict__ emb,
                                                const float* __restrict__ W1) {
    __shared__ float se[PW][64];
    __shared__ int s_pn, s_pb;
    int tid = threadIdx.x;
    if (tid == 0) { s_pn = g_pn; s_pb = g_pbase; }
    __syncthreads();
    const int pn = s_pn;
    if (pn == 0) return;
    int col = blockIdx.x * 128 + tid;
    int kc = blockIdx.y, dbase = kc * 64;
    for (int i = tid; i < PW * 64; i += 128) {
        int j = i >> 6, dd = i & 63;
        se[j][dd] = (j < pn) ? emb[(size_t)g_tok[s_pb + j] * DIM + dbase + dd] : 0.f;
    }
    __syncthreads();
    float acc[PW] = {0.f, 0.f, 0.f, 0.f};
    #pragma unroll 4
    for (int dd = 0; dd < 64; dd++) {
        float w = W1[(size_t)(dbase + dd) * DIM + col];
        #pragma unroll
        for (int j = 0; j < PW; j++) acc[j] += se[j][dd] * w;
    }
    #pragma unroll
    for (int j = 0; j < PW; j++) g_hp[kc][j][col] = acc[j];
}

// row-count-specialized split-K accumulate (static register indices)
template<int NA>
__device__ __forceinline__ void accumL(const float* __restrict__ Wout,
                                       const float (*sh)[64], int dc, int c) {
    float4 acc[NA];
    #pragma unroll
    for (int r = 0; r < NA; r++) acc[r] = make_float4(0.f, 0.f, 0.f, 0.f);
    const float* W = Wout + (size_t)dc * 64 * VOCAB + c;
    #pragma unroll 4
    for (int dd = 0; dd < 64; dd++) {
        float4 w = *(const float4*)(W + (size_t)dd * VOCAB);
        #pragma unroll
        for (int r = 0; r < NA; r++) {
            float s = sh[r][dd];
            acc[r].x += s * w.x; acc[r].y += s * w.y;
            acc[r].z += s * w.z; acc[r].w += s * w.w;
        }
    }
    #pragma unroll
    for (int r = 0; r < NA; r++)
        *(float4*)&g_lpart[dc][r][c] = acc[r];
}

// logits partials with fused h-combine+tanh: grid (63, NDCL), block 128
__global__ __launch_bounds__(128) void k_logits(const float* __restrict__ Wout) {
    __shared__ float sh[PW][64];
    __shared__ int s_pn;
    int tid = threadIdx.x, dc = blockIdx.y;
    if (tid == 0) s_pn = g_pn;
    __syncthreads();
    const int pn = s_pn;
    if (pn == 0) return;
    for (int i = tid; i < PW * 64; i += 128) {
        int j = i >> 6, dd = i & 63;
        float s = 0.f;
        if (j < pn) {
            int col = dc * 64 + dd;
            #pragma unroll
            for (int kc = 0; kc < KC; kc++) s += g_hp[kc][j][col];
            s = tanhf(s);
        }
        sh[j][dd] = s;
    }
    __syncthreads();
    int c = blockIdx.x * 512 + tid * 4;
    if (c >= VOCAB) return;
    switch (pn) {
        case 1: accumL<1>(Wout, sh, dc, c); break;
        case 2: accumL<2>(Wout, sh, dc, c); break;
        case 3: accumL<3>(Wout, sh, dc, c); break;
        default: accumL<PW>(Wout, sh, dc, c); break;
    }
}

// combine + penalty + per-64-chunk wave stats: grid (125, PW), block 256
__global__ __launch_bounds__(256) void k_comb_stats() {
    int j = blockIdx.y;
    if (j >= g_pn) return;
    int slot = g_pbase + j;
    int wv = threadIdx.x >> 6, lane = threadIdx.x & 63;
    int chunk = blockIdx.x * 4 + wv;             // < 500
    int c = chunk * 64 + lane;
    float v = 0.f;
    #pragma unroll
    for (int dc = 0; dc < NDCL; dc++) v += g_lpart[dc][j][c];
    if (c == EXPAND_ID) v -= 1e9f;
    g_rows[slot][c] = v;
    float bv = v; int bi = c;
    #pragma unroll
    for (int off = 1; off < 64; off <<= 1) {
        float ov = __shfl_xor(bv, off, 64);
        int   oi = __shfl_xor(bi, off, 64);
        if (ov > bv || (ov == bv && oi < bi)) { bv = ov; bi = oi; }
    }
    float z = expf(v - bv);
    #pragma unroll
    for (int off = 1; off < 64; off <<= 1)
        z += __shfl_xor(z, off, 64);
    if (lane == 0) {
        g_cmax[slot][chunk]  = bv;
        g_camax[slot][chunk] = bi;
        g_cz[slot][chunk]    = z;
    }
}

// tiny: per new row, full argmax (first-index) -> next-pass tokens (dedup)
__global__ __launch_bounds__(512) void k_next() {
    __shared__ float rf[512];
    __shared__ int   ri[512];
    __shared__ int s_pn, s_pb;
    int tid = threadIdx.x;
    if (tid == 0) { s_pn = g_pn; s_pb = g_pbase; }
    __syncthreads();
    const int pn = s_pn, base = s_pb;
    for (int j = 0; j < pn; j++) {
        int slot = base + j;
        float bv = NEGF; int bi = 0x7fffffff;
        if (tid < NCH) { bv = g_cmax[slot][tid]; bi = g_camax[slot][tid]; }
        rf[tid] = bv; ri[tid] = bi;
        __syncthreads();
        for (int o = 256; o; o >>= 1) {
            if (tid < o) {
                if (rf[tid + o] > rf[tid] ||
                    (rf[tid + o] == rf[tid] && ri[tid + o] < ri[tid])) {
                    rf[tid] = rf[tid + o]; ri[tid] = ri[tid + o];
                }
            }
            __syncthreads();
        }
        if (tid == 0) g_rowx0[slot] = ri[0];
        __syncthreads();
    }
    if (tid == 0) {
        int nt = g_ntok;
        int nb = nt;
        for (int j = 0; j < pn; j++) {
            int t = g_rowx0[base + j];
            bool found = false;
            for (int k = 0; k < nt; k++) if (g_tok[k] == t) { found = true; break; }
            if (!found && nt < ROWS) g_tok[nt++] = t;
        }
        g_pbase = nb; g_pn = nt - nb; g_ntok = nt;
    }
}

// per-row conf, fully parallel across rows: grid ROWS, block 1024
__global__ __launch_bounds__(1024) void k_conf() {
    int slot = blockIdx.x;
    if (slot >= g_pbase) return;        // only rows with computed data
    __shared__ float rf[1024];
    __shared__ float cmv[512];
    __shared__ float cand[CAP];
    __shared__ float sorted_[TOPK];
    __shared__ int s_n;
    __shared__ float s_mx, s_Z;
    __shared__ unsigned s_thr;
    int tid = threadIdx.x;
    // row max
    rf[tid] = (tid < NCH) ? g_cmax[slot][tid] : NEGF;
    __syncthreads();
    for (int o = 512; o; o >>= 1) {
        if (tid < o) rf[tid] = fmaxf(rf[tid], rf[tid + o]);
        __syncthreads();
    }
    if (tid == 0) s_mx = rf[0];
    __syncthreads();
    float mx = s_mx;
    // Z
    rf[tid] = (tid < NCH) ? g_cz[slot][tid] * expf(g_cmax[slot][tid] - mx) : 0.f;
    __syncthreads();
    for (int o = 512; o; o >>= 1) {
        if (tid < o) rf[tid] += rf[tid + o];
        __syncthreads();
    }
    if (tid == 0) { s_Z = rf[0]; s_n = 0; }
    __syncthreads();
    // threshold: 50th-largest chunk max (rank-select over 500)
    if (tid < 512) cmv[tid] = (tid < NCH) ? g_cmax[slot][tid] : NEGF;
    __syncthreads();
    if (tid < NCH) {
        unsigned kt = keyf(cmv[tid]);
        int rank = 0;
        for (int j = 0; j < NCH; j++) {
            unsigned kj = keyf(cmv[j]);
            rank += (kj > kt) || (kj == kt && j < tid);
        }
        if (rank == THRRANK) s_thr = kt;
    }
    __syncthreads();
    unsigned T = s_thr;
    // gather candidates >= T
    const float4* L4 = (const float4*)g_rows[slot];
    for (int i = tid; i < VOCAB / 4; i += 1024) {
        float4 v4 = L4[i];
        float vv[4] = {v4.x, v4.y, v4.z, v4.w};
        #pragma unroll
        for (int q = 0; q < 4; q++) {
            if (keyf(vv[q]) >= T) {
                int j = atomicAdd(&s_n, 1);
                if (j < CAP) cand[j] = vv[q];
            }
        }
    }
    __syncthreads();
    int n = s_n; if (n > CAP) n = CAP;
    // rank-sort top-50 (distinct keys -> order-independent)
    for (int i = tid; i < n; i += 1024) {
        unsigned ki = keyf(cand[i]);
        int rank = 0;
        for (int j = 0; j < n; j++) {
            unsigned kj = keyf(cand[j]);
            rank += (kj > ki) || (kj == ki && j < i);
        }
        if (rank < TOPK) sorted_[rank] = cand[i];
    }
    __syncthreads();
    if (tid == 0) {
        int m = n; if (m > TOPK) m = TOPK;
        float run = expf(sorted_[0] - mx);       // == 1
        float lim = 0.9f * s_Z;
        for (int j = 1; j < m; j++) {
            if (run > lim) break;                // top-p removal boundary
            run += expf(sorted_[j] - mx);
        }
        g_rowconf[slot] = 1.0f / run;
    }
}

// 1 block, 1024 threads: replay all 4 selection steps in LDS + write output
__global__ __launch_bounds__(1024) void k_select(float* __restrict__ out) {
    __shared__ int   xl[BS];
    __shared__ float rf[1024];
    __shared__ int   ri[1024];
    __shared__ int   px0[BS];
    __shared__ int   rtok[ROWS];
    __shared__ float rcf[ROWS];
    __shared__ int   rx0[ROWS];
    __shared__ float stepc[NSTEPS];
    __shared__ int s_nt;
    int p = threadIdx.x;
    xl[p] = g_x[p];
    if (p < ROWS) { rtok[p] = g_tok[p]; rcf[p] = g_rowconf[p]; rx0[p] = g_rowx0[p]; }
    if (p == 0) s_nt = g_pbase;              // computed rows only
    __syncthreads();
    const int nt = s_nt;
    for (int step = 0; step < NSTEPS; step++) {
        float mc = NEGF; int mx0 = 0;
        if (xl[p] == MASK_ID) {
            int s = p & (SS - 1);
            int t = xl[(s == 0) ? p : p - 1];
            for (int k = 0; k < nt; k++) {
                if (rtok[k] == t) { mc = rcf[k]; mx0 = rx0[k]; break; }
            }
        }
        px0[p] = mx0;
        rf[p] = mc; ri[p] = p;
        __syncthreads();
        for (int o = 512; o; o >>= 1) {
            if (p < o) {
                if (rf[p + o] > rf[p] ||
                    (rf[p + o] == rf[p] && ri[p + o] < ri[p])) {
                    rf[p] = rf[p + o]; ri[p] = ri[p + o];
                }
            }
            __syncthreads();
        }
        if (p == 0) {
            stepc[step] = rf[0];
            if (rf[0] > 0.f) xl[ri[0]] = px0[ri[0]];   // any-mask guard
        }
        __syncthreads();
    }
    out[p] = (float)xl[p];
    if (p < NSTEPS) out[BS + p] = stepc[p];
}

extern "C" void kernel_launch(void* const* d_in, const int* in_sizes, int n_in,
                              void* d_out, int out_size, void* d_ws, size_t ws_size,
                              hipStream_t stream) {
    const int*   x    = (const int*)  d_in[0];
    const float* emb  = (const float*)d_in[1];
    const float* W1   = (const float*)d_in[2];
    const float* Wout = (const float*)d_in[3];
    float*       out  = (float*)d_out;

    k_start<<<1, 1024, 0, stream>>>(x);
    for (int pass = 0; pass < NSTEPS; pass++) {
        k_h_part<<<dim3(8, KC), 128, 0, stream>>>(emb, W1);
        k_logits<<<dim3(63, NDCL), 128, 0, stream>>>(Wout);
        k_comb_stats<<<dim3(125, PW), 256, 0, stream>>>();
        k_next<<<1, 512, 0, stream>>>();
    }
    k_conf<<<ROWS, 1024, 0, stream>>>();
    k_select<<<1, 1024, 0, stream>>>(out);
}